// Round 12
// baseline (625.229 us; speedup 1.0000x reference)
//
#include <hip/hip_runtime.h>
#include <math.h>

#define BB 32
#define TT 512
#define DW 128
#define DC 64
#define DD 192
#define HH 128
#define G4 512
#define LL 32

typedef __fp16 h2_t __attribute__((ext_vector_type(2)));

__device__ __forceinline__ h2_t bch2(unsigned int x) { return __builtin_bit_cast(h2_t, x); }

// quad_perm lane-xor via DPP (VALU, not LDS)
__device__ __forceinline__ float qxor1(float x) {
    return __int_as_float(__builtin_amdgcn_update_dpp(0, __float_as_int(x), 0xB1, 0xF, 0xF, true));
}
__device__ __forceinline__ float qxor2(float x) {
    return __int_as_float(__builtin_amdgcn_update_dpp(0, __float_as_int(x), 0x4E, 0xF, 0xF, true));
}
// quad_perm broadcast of lane q (within each quad)
__device__ __forceinline__ float qbcast(float x, int ctrl_imm) {
    switch (ctrl_imm) {
        case 0: return __int_as_float(__builtin_amdgcn_update_dpp(0, __float_as_int(x), 0x00, 0xF, 0xF, true));
        case 1: return __int_as_float(__builtin_amdgcn_update_dpp(0, __float_as_int(x), 0x55, 0xF, 0xF, true));
        case 2: return __int_as_float(__builtin_amdgcn_update_dpp(0, __float_as_int(x), 0xAA, 0xF, 0xF, true));
        default:return __int_as_float(__builtin_amdgcn_update_dpp(0, __float_as_int(x), 0xFF, 0xF, 0xF, true));
    }
}

// ---------------------------------------------------------------------------
// K1: fused embedding-gather + input projection GEMM, f16 dot2, single-stage.
// Also zeroes out[0] (needed by k_crf's atomicAdd).
// ---------------------------------------------------------------------------
__global__ __launch_bounds__(512) void k_inproj(
    const int* __restrict__ word, const int* __restrict__ charr,
    const float* __restrict__ wemb, const float* __restrict__ cemb,
    const float* __restrict__ Wf, const float* __restrict__ bf,
    const float* __restrict__ Wb, const float* __restrict__ bb,
    float* __restrict__ xpf, float* __restrict__ xpb,
    float* __restrict__ out)
{
    __shared__ __align__(16) h2_t As2[96][132];   // [k-pair][token-row]
    __shared__ __align__(16) h2_t Bs2[96][260];   // [k-pair][gate-col]
    const int tid = threadIdx.x;
    const int ntile = blockIdx.x;           // 0..127
    const int ctile = blockIdx.y;           // 0..3
    if (ntile == 0 && ctile == 0 && tid == 0) out[0] = 0.f;
    const int dir = ctile >> 1;
    const float* W = dir ? Wb : Wf;
    const float* bias = dir ? bb : bf;
    float* xp = dir ? xpb : xpf;
    const int colbase = (ctile & 1) * 256;  // within the 512 gate-cols

    // ---- stage A: 128 tokens x 192 floats -> h2 (4 threads per row) ----
    {
        const int lrow = tid >> 2;          // 0..127
        const int lq   = tid & 3;
        const int nA   = ntile * 128 + lrow;
        const int wi   = word[nA];
        const int ci   = charr[nA];
#pragma unroll
        for (int kc = 0; kc < 12; ++kc) {
            const int k0 = kc * 16 + lq * 4;
            float4 av;
            if (k0 < DW) av = *(const float4*)(wemb + (size_t)wi * DW + k0);
            else         av = *(const float4*)(cemb + (size_t)ci * DC + (k0 - DW));
            const int kp = k0 >> 1;
            As2[kp    ][lrow] = __builtin_amdgcn_cvt_pkrtz(av.x, av.y);
            As2[kp + 1][lrow] = __builtin_amdgcn_cvt_pkrtz(av.z, av.w);
        }
    }
    // ---- stage B: 256 gate-cols x 192 floats -> h2 (2 threads per col) ----
    {
        const int lcol = tid >> 1;          // 0..255
        const int lh   = tid & 1;
        const int g    = colbase + lcol;
#pragma unroll
        for (int kc = 0; kc < 24; ++kc) {
            const int k0 = kc * 8 + lh * 4;
            const float4 bv = *(const float4*)(W + (size_t)g * DD + k0);
            const int kp = k0 >> 1;
            Bs2[kp    ][lcol] = __builtin_amdgcn_cvt_pkrtz(bv.x, bv.y);
            Bs2[kp + 1][lcol] = __builtin_amdgcn_cvt_pkrtz(bv.z, bv.w);
        }
    }
    __syncthreads();

    // ---- compute: 8x8 outputs per thread over 96 k-pairs, no barriers ----
    const int tr = tid >> 5;    // 0..15  (token block)
    const int tc = tid & 31;    // 0..31  (col block)
    float acc[8][8];
#pragma unroll
    for (int i = 0; i < 8; ++i)
#pragma unroll
        for (int j = 0; j < 8; ++j) acc[i][j] = 0.f;

    for (int kc = 0; kc < 24; ++kc) {
#pragma unroll
        for (int kq = 0; kq < 4; ++kq) {
            const int kp = kc * 4 + kq;
            h2_t __attribute__((aligned(16))) a2[8], b2[8];
            *(uint4*)&a2[0] = *(const uint4*)&As2[kp][tr * 8];
            *(uint4*)&a2[4] = *(const uint4*)&As2[kp][tr * 8 + 4];
            *(uint4*)&b2[0] = *(const uint4*)&Bs2[kp][tc * 8];
            *(uint4*)&b2[4] = *(const uint4*)&Bs2[kp][tc * 8 + 4];
#pragma unroll
            for (int i = 0; i < 8; ++i)
#pragma unroll
                for (int j = 0; j < 8; ++j)
                    acc[i][j] = __builtin_amdgcn_fdot2(a2[i], b2[j], acc[i][j], false);
        }
    }
#pragma unroll
    for (int i = 0; i < 8; ++i) {
        const int n  = ntile * 128 + tr * 8 + i;
        const int b_ = n >> 9, t_ = n & 511;
        float* dst = xp + ((size_t)(t_ * BB + b_)) * G4 + colbase + tc * 8;
#pragma unroll
        for (int j = 0; j < 8; ++j) dst[j] = acc[i][j] + bias[colbase + tc * 8 + j];
    }
}

// ---------------------------------------------------------------------------
// K2: LSTM scan v10 — TWO SAMPLES PER BLOCK VIA WAVES. 32 blocks, 1024 thr.
// Waves 0-7 run sample A (smp=0), waves 8-15 sample B (smp=1); per-thread
// structure is R7 verbatim (88-VGPR envelope, 64 weight VGPRs). Shared
// barrier is harmless (both recurrences are in lockstep); 4 waves/SIMD
// double the latency-hiding pool and amortize barrier cost over 2 samples.
// ---------------------------------------------------------------------------
__global__ __launch_bounds__(1024)
__attribute__((amdgpu_waves_per_eu(4, 4)))
void k_lstm(
    const float* __restrict__ xpf, const float* __restrict__ xpb,
    const float* __restrict__ Whf, const float* __restrict__ Whb,
    __fp16* __restrict__ hf, __fp16* __restrict__ hb)
{
    // [buf][smp][ks*40 + j] f16; smp offset = 320 B (16-bank shift), all
    // lanes of a wave share one smp -> conflict pattern identical to R7.
    __shared__ __align__(16) __fp16 hsd[2][2][160];
    const int tid  = threadIdx.x;
    const int smp  = tid >> 9;       // 0 or 1 (wave group)
    const int tid9 = tid & 511;
    const int dir  = blockIdx.x >> 4;
    const int b_   = ((blockIdx.x & 15) << 1) + smp;
    const float* xp = dir ? xpb : xpf;
    const float* Wh = dir ? Whb : Whf;
    __fp16* hout = dir ? hb : hf;
    const int ks = tid9 & 3;         // k-quarter (32 wide) == owned gate id
    const int u  = tid9 >> 2;        // hidden unit 0..127

    // W_hh[g*128+u][ks*32 .. +31] for g=0..3 as packed half2: 4x16 = 64 VGPRs
    h2_t w2[4][16];
#pragma unroll
    for (int g = 0; g < 4; ++g) {
        const float2* wp = (const float2*)(Wh + (size_t)(g * 128 + u) * HH + ks * 32);
#pragma unroll
        for (int j = 0; j < 16; ++j)
            w2[g][j] = __builtin_amdgcn_cvt_pkrtz(wp[j].x, wp[j].y);
    }

    const float mk0 = (ks == 0) ? 1.f : 0.f;
    const float mk1 = (ks == 1) ? 1.f : 0.f;
    const float mk2 = (ks == 2) ? 1.f : 0.f;
    const float mk3 = (ks == 3) ? 1.f : 0.f;
    const bool istanh = (ks == 2);
    const float GS  = istanh ? 2.f : -1.f;
    const float GC0 = istanh ? 1.f : 0.f;
    const float GC1 = istanh ? -2.f : 1.f;
    const bool ks1 = (ks & 1) != 0;
    const bool ks2 = (ks & 2) != 0;

    if (tid < 320) ((unsigned int*)&hsd[0][0][0])[tid] = 0u;  // zero both bufs
    float c = 0.f;
    const int t0 = dir ? (TT - 1) : 0;
    const int tstep = dir ? -1 : 1;
    const int xstride = tstep * BB * G4;
    const int hstride = tstep * BB * HH;
    const float* xqp = xp + ((long long)t0 * BB + b_) * G4 + ks * 128 + u;
    __fp16*      hop = hout + ((long long)t0 * BB + b_) * HH + u;
    float xq = *xqp;
    __syncthreads();

    for (int s = 0; s < TT; ++s) {
        const int rb = s & 1;
        float p0 = mk0 * xq, p1 = mk1 * xq, p2 = mk2 * xq, p3 = mk3 * xq;
        // prefetch next xp now (one-past-end lands in adjacent ws buffer)
        xqp += xstride;
        xq = *xqp;
#pragma unroll
        for (int q = 0; q < 4; ++q) {
            const uint4 hv = *(const uint4*)&hsd[rb][smp][ks * 40 + q * 8];
            const h2_t ha  = bch2(hv.x);
            const h2_t hbv = bch2(hv.y);
            const h2_t hc  = bch2(hv.z);
            const h2_t hd  = bch2(hv.w);
            p0 = __builtin_amdgcn_fdot2(ha,  w2[0][q*4+0], p0, false);
            p0 = __builtin_amdgcn_fdot2(hbv, w2[0][q*4+1], p0, false);
            p0 = __builtin_amdgcn_fdot2(hc,  w2[0][q*4+2], p0, false);
            p0 = __builtin_amdgcn_fdot2(hd,  w2[0][q*4+3], p0, false);
            p1 = __builtin_amdgcn_fdot2(ha,  w2[1][q*4+0], p1, false);
            p1 = __builtin_amdgcn_fdot2(hbv, w2[1][q*4+1], p1, false);
            p1 = __builtin_amdgcn_fdot2(hc,  w2[1][q*4+2], p1, false);
            p1 = __builtin_amdgcn_fdot2(hd,  w2[1][q*4+3], p1, false);
            p2 = __builtin_amdgcn_fdot2(ha,  w2[2][q*4+0], p2, false);
            p2 = __builtin_amdgcn_fdot2(hbv, w2[2][q*4+1], p2, false);
            p2 = __builtin_amdgcn_fdot2(hc,  w2[2][q*4+2], p2, false);
            p2 = __builtin_amdgcn_fdot2(hd,  w2[2][q*4+3], p2, false);
            p3 = __builtin_amdgcn_fdot2(ha,  w2[3][q*4+0], p3, false);
            p3 = __builtin_amdgcn_fdot2(hbv, w2[3][q*4+1], p3, false);
            p3 = __builtin_amdgcn_fdot2(hc,  w2[3][q*4+2], p3, false);
            p3 = __builtin_amdgcn_fdot2(hd,  w2[3][q*4+3], p3, false);
        }
        // quad butterfly: every lane ends with ALL four complete gate sums
        p0 += qxor1(p0); p0 += qxor2(p0);
        p1 += qxor1(p1); p1 += qxor2(p1);
        p2 += qxor1(p2); p2 += qxor2(p2);
        p3 += qxor1(p3); p3 += qxor2(p3);
        // lane ks computes only its gate's nonlinearity, quad_perm regather
        const float pa   = ks1 ? p1 : p0;
        const float pb   = ks1 ? p3 : p2;
        const float psel = ks2 ? pb : pa;
        const float val  = GC0 + GC1 * __builtin_amdgcn_rcpf(1.f + __expf(GS * psel));
        const float gi = qbcast(val, 0);
        const float gf = qbcast(val, 1);
        const float gg = qbcast(val, 2);
        const float go = qbcast(val, 3);
        c = gf * c + gi * gg;
        const float tc = 1.f - 2.f * __builtin_amdgcn_rcpf(1.f + __expf(2.f * c));
        const float hv = go * tc;
        const __fp16 hv16 = (__fp16)hv;
        if (ks == 0) {
            hsd[rb ^ 1][smp][(u >> 5) * 40 + (u & 31)] = hv16;
            *hop = hv16;
        }
        hop += hstride;
        // raw barrier, NO memory clobber: order only LDS (lgkm), leave
        // global store + prefetch load in flight.
        __builtin_amdgcn_sched_barrier(0);
        asm volatile("s_waitcnt lgkmcnt(0)");
        __builtin_amdgcn_s_barrier();
        __builtin_amdgcn_sched_barrier(0);
    }
}

// ---------------------------------------------------------------------------
// K3: emit[t][b][l] = (concat(hf,hb)[t][b][:] . W_out[l,:] + b_out[l]) * mask
// f16 staging + fdot2; wsm2 pitch 130 dwords -> 2-way bank alias (free).
// ---------------------------------------------------------------------------
__global__ __launch_bounds__(1024) void k_emit(
    const __fp16* __restrict__ hf, const __fp16* __restrict__ hb,
    const float* __restrict__ Wout, const float* __restrict__ bout,
    const int* __restrict__ charr, float* __restrict__ emit)
{
    __shared__ __align__(16) unsigned int hsm2[BB * 132];   // [b][132] h2-pitch
    __shared__ __align__(16) unsigned int wsm2[LL * 130];   // [l][130] h2-pitch
    const int t = blockIdx.x;
    const int tid = threadIdx.x;
    // stage h: 32 b x 128 h2 (64 from hf, 64 from hb)
    const unsigned int* hfu = (const unsigned int*)hf;
    const unsigned int* hbu = (const unsigned int*)hb;
    for (int idx = tid; idx < BB * 128; idx += 1024) {
        const int b_ = idx >> 7, k = idx & 127;
        const unsigned int v = (k < 64)
            ? hfu[((size_t)t * BB + b_) * 64 + k]
            : hbu[((size_t)t * BB + b_) * 64 + (k - 64)];
        hsm2[b_ * 132 + k] = v;
    }
    // stage Wout: 32 l x 128 h2 (cvt f32->f16)
    for (int idx = tid; idx < LL * 128; idx += 1024) {
        const int l = idx >> 7, kp = idx & 127;
        const float2 wv = ((const float2*)Wout)[l * 128 + kp];
        wsm2[l * 130 + kp] = __builtin_bit_cast(unsigned int,
            __builtin_amdgcn_cvt_pkrtz(wv.x, wv.y));
    }
    __syncthreads();
    const int b_ = tid >> 5, l = tid & 31;
    float acc = bout[l];
#pragma unroll 8
    for (int q = 0; q < 32; ++q) {
        const uint4 h4 = *(const uint4*)&hsm2[b_ * 132 + q * 4];
        const uint2 wa = *(const uint2*)&wsm2[l * 130 + q * 4];
        const uint2 wb = *(const uint2*)&wsm2[l * 130 + q * 4 + 2];
        acc = __builtin_amdgcn_fdot2(bch2(h4.x), bch2(wa.x), acc, false);
        acc = __builtin_amdgcn_fdot2(bch2(h4.y), bch2(wa.y), acc, false);
        acc = __builtin_amdgcn_fdot2(bch2(h4.z), bch2(wb.x), acc, false);
        acc = __builtin_amdgcn_fdot2(bch2(h4.w), bch2(wb.y), acc, false);
    }
    const float m = (charr[b_ * TT + t] > 0) ? 1.f : 0.f;
    emit[((size_t)t * BB + b_) * LL + l] = acc * m;
}

// ---------------------------------------------------------------------------
// K4: CRF forward + gold score, fused. 32 blocks x 64 threads.
// ---------------------------------------------------------------------------
__global__ __launch_bounds__(64) void k_crf(
    const float* __restrict__ emit, const int* __restrict__ charr,
    const int* __restrict__ y, const float* __restrict__ trans,
    const float* __restrict__ startv, const float* __restrict__ endv,
    float* __restrict__ out)
{
    const int tid = threadIdx.x;             // lanes 32..63 mirror lanes 0..31
    const int b_ = blockIdx.x;
    const int j = tid & 31;

    // ---- gold path score: lane-parallel over t (stride 64) ----
    float sc = 0.f;
    int ms = 0;
    for (int t = tid; t < TT; t += 64) {
        const int yv = y[b_ * TT + t];
        const int m = (charr[b_ * TT + t] > 0);
        if (m) { sc += emit[((size_t)t * BB + b_) * LL + yv]; ms++; }
        if (t + 1 < TT) {
            const int mn = (charr[b_ * TT + t + 1] > 0);
            if (mn) sc += trans[yv * LL + y[b_ * TT + t + 1]];
        }
    }
#pragma unroll
    for (int o = 32; o; o >>= 1) {
        sc += __shfl_xor(sc, o);
        ms += __shfl_xor(ms, o);
    }

    // ---- CRF forward ----
    float et[32];
#pragma unroll
    for (int i = 0; i < 32; ++i) et[i] = __expf(trans[i * LL + j]);

    const float a0 = startv[j] + emit[(size_t)b_ * LL + j];
    float M = a0;
    M = fmaxf(M, __shfl_xor(M, 16));
    M = fmaxf(M, __shfl_xor(M, 8));
    M = fmaxf(M, __shfl_xor(M, 4));
    M = fmaxf(M, __shfl_xor(M, 2));
    M = fmaxf(M, __shfl_xor(M, 1));
    float A = __expf(a0 - M);
    float logsc = M;

    float e_nx = emit[((size_t)1 * BB + b_) * LL + j];
    int   m_nx = charr[b_ * TT + 1];

    for (int t = 1; t < TT; ++t) {
        const float ee = __expf(e_nx);       // off critical chain (prefetched)
        const int m_cur = m_nx;
        if (t + 1 < TT) {
            e_nx = emit[((size_t)(t + 1) * BB + b_) * LL + j];
            m_nx = charr[b_ * TT + t + 1];
        }
        float s0 = 0.f, s1 = 0.f, s2 = 0.f, s3 = 0.f;
#pragma unroll
        for (int i = 0; i < 32; i += 4) {
            s0 = fmaf(__int_as_float(__builtin_amdgcn_readlane(__float_as_int(A), i    )), et[i    ], s0);
            s1 = fmaf(__int_as_float(__builtin_amdgcn_readlane(__float_as_int(A), i + 1)), et[i + 1], s1);
            s2 = fmaf(__int_as_float(__builtin_amdgcn_readlane(__float_as_int(A), i + 2)), et[i + 2], s2);
            s3 = fmaf(__int_as_float(__builtin_amdgcn_readlane(__float_as_int(A), i + 3)), et[i + 3], s3);
        }
        const float Anew = ((s0 + s1) + (s2 + s3)) * ee;
        A = (m_cur > 0) ? Anew : A;
        if ((t & 7) == 0) {                  // renorm every 8 steps
            float S = A;
            S = fmaxf(S, __shfl_xor(S, 16));
            S = fmaxf(S, __shfl_xor(S, 8));
            S = fmaxf(S, __shfl_xor(S, 4));
            S = fmaxf(S, __shfl_xor(S, 2));
            S = fmaxf(S, __shfl_xor(S, 1));
            A *= __builtin_amdgcn_rcpf(S);
            logsc += __logf(S);
        }
    }
    // finalize: alpha_j = log(A_j) + logsc; logZ = LSE_j(alpha_j + end_j)
    const float z = __logf(A) + logsc + endv[j];
    float Mz = z;
    Mz = fmaxf(Mz, __shfl_xor(Mz, 16));
    Mz = fmaxf(Mz, __shfl_xor(Mz, 8));
    Mz = fmaxf(Mz, __shfl_xor(Mz, 4));
    Mz = fmaxf(Mz, __shfl_xor(Mz, 2));
    Mz = fmaxf(Mz, __shfl_xor(Mz, 1));
    float sz = __expf(z - Mz);
    sz += __shfl_xor(sz, 16);
    sz += __shfl_xor(sz, 8);
    sz += __shfl_xor(sz, 4);
    sz += __shfl_xor(sz, 2);
    sz += __shfl_xor(sz, 1);
    if (tid == 0) {
        const float logZ = Mz + __logf(sz);
        int last = ms - 1;
        if (last < 0) last = 0;
        const float gold = startv[y[b_ * TT]] + sc + endv[y[b_ * TT + last]];
        atomicAdd(out, logZ - gold);
    }
}

extern "C" void kernel_launch(void* const* d_in, const int* in_sizes, int n_in,
                              void* d_out, int out_size, void* d_ws, size_t ws_size,
                              hipStream_t stream) {
    (void)in_sizes; (void)n_in; (void)out_size; (void)ws_size;
    const int*   word  = (const int*)d_in[0];
    const int*   charr = (const int*)d_in[1];
    const int*   yv    = (const int*)d_in[2];
    const float* wemb  = (const float*)d_in[3];
    const float* cemb  = (const float*)d_in[4];
    const float* Wihf  = (const float*)d_in[5];
    const float* Whhf  = (const float*)d_in[6];
    const float* bf    = (const float*)d_in[7];
    const float* Wihb  = (const float*)d_in[8];
    const float* Whhb  = (const float*)d_in[9];
    const float* bb    = (const float*)d_in[10];
    const float* Wout  = (const float*)d_in[11];
    const float* bout  = (const float*)d_in[12];
    const float* trans = (const float*)d_in[13];
    const float* startv= (const float*)d_in[14];
    const float* endv  = (const float*)d_in[15];

    float* ws    = (float*)d_ws;
    float* xpf   = ws;                          // [T][B][512] f32
    float* xpb   = xpf + (size_t)TT * BB * G4;
    __fp16* hf16 = (__fp16*)(xpb + (size_t)TT * BB * G4);  // [T][B][128] f16
    __fp16* hb16 = hf16 + (size_t)TT * BB * HH;
    float* emit  = (float*)(hb16 + (size_t)TT * BB * HH);  // [T][B][32] f32

    k_inproj<<<dim3(128, 4), 512, 0, stream>>>(word, charr, wemb, cemb,
                                               Wihf, bf, Wihb, bb, xpf, xpb,
                                               (float*)d_out);
    k_lstm<<<32, 1024, 0, stream>>>(xpf, xpb, Whhf, Whhb, hf16, hb16);
    k_emit<<<TT, 1024, 0, stream>>>(hf16, hb16, Wout, bout, charr, emit);
    k_crf<<<32, 64, 0, stream>>>(emit, charr, yv, trans, startv, endv,
                                 (float*)d_out);
}

// Round 13
// 463.212 us; speedup vs baseline: 1.3498x; 1.3498x over previous
//
#include <hip/hip_runtime.h>
#include <math.h>

#define BB 32
#define TT 512
#define DW 128
#define DC 64
#define DD 192
#define HH 128
#define G4 512
#define LL 32

typedef __fp16 h2_t __attribute__((ext_vector_type(2)));

__device__ __forceinline__ h2_t bch2(unsigned int x) { return __builtin_bit_cast(h2_t, x); }

// quad_perm lane-xor via DPP (VALU, not LDS)
__device__ __forceinline__ float qxor1(float x) {
    return __int_as_float(__builtin_amdgcn_update_dpp(0, __float_as_int(x), 0xB1, 0xF, 0xF, true));
}
__device__ __forceinline__ float qxor2(float x) {
    return __int_as_float(__builtin_amdgcn_update_dpp(0, __float_as_int(x), 0x4E, 0xF, 0xF, true));
}
// quad_perm broadcast of lane q (within each quad)
__device__ __forceinline__ float qbcast(float x, int ctrl_imm) {
    switch (ctrl_imm) {
        case 0: return __int_as_float(__builtin_amdgcn_update_dpp(0, __float_as_int(x), 0x00, 0xF, 0xF, true));
        case 1: return __int_as_float(__builtin_amdgcn_update_dpp(0, __float_as_int(x), 0x55, 0xF, 0xF, true));
        case 2: return __int_as_float(__builtin_amdgcn_update_dpp(0, __float_as_int(x), 0xAA, 0xF, 0xF, true));
        default:return __int_as_float(__builtin_amdgcn_update_dpp(0, __float_as_int(x), 0xFF, 0xF, 0xF, true));
    }
}

// ---------------------------------------------------------------------------
// K1: fused embedding-gather + input projection GEMM, f16 dot2, single-stage.
// Also zeroes out[0] (needed by k_crf's atomicAdd).
// ---------------------------------------------------------------------------
__global__ __launch_bounds__(512) void k_inproj(
    const int* __restrict__ word, const int* __restrict__ charr,
    const float* __restrict__ wemb, const float* __restrict__ cemb,
    const float* __restrict__ Wf, const float* __restrict__ bf,
    const float* __restrict__ Wb, const float* __restrict__ bb,
    float* __restrict__ xpf, float* __restrict__ xpb,
    float* __restrict__ out)
{
    __shared__ __align__(16) h2_t As2[96][132];   // [k-pair][token-row]
    __shared__ __align__(16) h2_t Bs2[96][260];   // [k-pair][gate-col]
    const int tid = threadIdx.x;
    const int ntile = blockIdx.x;           // 0..127
    const int ctile = blockIdx.y;           // 0..3
    if (ntile == 0 && ctile == 0 && tid == 0) out[0] = 0.f;
    const int dir = ctile >> 1;
    const float* W = dir ? Wb : Wf;
    const float* bias = dir ? bb : bf;
    float* xp = dir ? xpb : xpf;
    const int colbase = (ctile & 1) * 256;  // within the 512 gate-cols

    // ---- stage A: 128 tokens x 192 floats -> h2 (4 threads per row) ----
    {
        const int lrow = tid >> 2;          // 0..127
        const int lq   = tid & 3;
        const int nA   = ntile * 128 + lrow;
        const int wi   = word[nA];
        const int ci   = charr[nA];
#pragma unroll
        for (int kc = 0; kc < 12; ++kc) {
            const int k0 = kc * 16 + lq * 4;
            float4 av;
            if (k0 < DW) av = *(const float4*)(wemb + (size_t)wi * DW + k0);
            else         av = *(const float4*)(cemb + (size_t)ci * DC + (k0 - DW));
            const int kp = k0 >> 1;
            As2[kp    ][lrow] = __builtin_amdgcn_cvt_pkrtz(av.x, av.y);
            As2[kp + 1][lrow] = __builtin_amdgcn_cvt_pkrtz(av.z, av.w);
        }
    }
    // ---- stage B: 256 gate-cols x 192 floats -> h2 (2 threads per col) ----
    {
        const int lcol = tid >> 1;          // 0..255
        const int lh   = tid & 1;
        const int g    = colbase + lcol;
#pragma unroll
        for (int kc = 0; kc < 24; ++kc) {
            const int k0 = kc * 8 + lh * 4;
            const float4 bv = *(const float4*)(W + (size_t)g * DD + k0);
            const int kp = k0 >> 1;
            Bs2[kp    ][lcol] = __builtin_amdgcn_cvt_pkrtz(bv.x, bv.y);
            Bs2[kp + 1][lcol] = __builtin_amdgcn_cvt_pkrtz(bv.z, bv.w);
        }
    }
    __syncthreads();

    // ---- compute: 8x8 outputs per thread over 96 k-pairs, no barriers ----
    const int tr = tid >> 5;    // 0..15  (token block)
    const int tc = tid & 31;    // 0..31  (col block)
    float acc[8][8];
#pragma unroll
    for (int i = 0; i < 8; ++i)
#pragma unroll
        for (int j = 0; j < 8; ++j) acc[i][j] = 0.f;

    for (int kc = 0; kc < 24; ++kc) {
#pragma unroll
        for (int kq = 0; kq < 4; ++kq) {
            const int kp = kc * 4 + kq;
            h2_t __attribute__((aligned(16))) a2[8], b2[8];
            *(uint4*)&a2[0] = *(const uint4*)&As2[kp][tr * 8];
            *(uint4*)&a2[4] = *(const uint4*)&As2[kp][tr * 8 + 4];
            *(uint4*)&b2[0] = *(const uint4*)&Bs2[kp][tc * 8];
            *(uint4*)&b2[4] = *(const uint4*)&Bs2[kp][tc * 8 + 4];
#pragma unroll
            for (int i = 0; i < 8; ++i)
#pragma unroll
                for (int j = 0; j < 8; ++j)
                    acc[i][j] = __builtin_amdgcn_fdot2(a2[i], b2[j], acc[i][j], false);
        }
    }
#pragma unroll
    for (int i = 0; i < 8; ++i) {
        const int n  = ntile * 128 + tr * 8 + i;
        const int b_ = n >> 9, t_ = n & 511;
        float* dst = xp + ((size_t)(t_ * BB + b_)) * G4 + colbase + tc * 8;
#pragma unroll
        for (int j = 0; j < 8; ++j) dst[j] = acc[i][j] + bias[colbase + tc * 8 + j];
    }
}

// ---------------------------------------------------------------------------
// K2: LSTM scan (R7/R11 structure — best measured: 268 us). 64 blocks,
// 512 threads, thread (u=tid>>2, ks=tid&3), weights resident (64 VGPRs),
// 88-VGPR envelope at 2 waves/SIMD. hout stored as __fp16.
// ---------------------------------------------------------------------------
__global__ __launch_bounds__(512)
__attribute__((amdgpu_waves_per_eu(2, 2)))
void k_lstm(
    const float* __restrict__ xpf, const float* __restrict__ xpb,
    const float* __restrict__ Whf, const float* __restrict__ Whb,
    __fp16* __restrict__ hf, __fp16* __restrict__ hb)
{
    // [buf][ks*40 + j] f16 units; per-ks block = 80 B -> conflict-free.
    __shared__ __align__(16) __fp16 hsd[2][160];
    const int tid = threadIdx.x;
    const int dir = blockIdx.x >> 5;
    const int b_  = blockIdx.x & 31;
    const float* xp = dir ? xpb : xpf;
    const float* Wh = dir ? Whb : Whf;
    __fp16* hout = dir ? hb : hf;
    const int ks = tid & 3;          // k-quarter (32 wide) == owned gate id
    const int u  = tid >> 2;         // hidden unit 0..127

    // W_hh[g*128+u][ks*32 .. +31] for g=0..3 as packed half2: 4x16 = 64 VGPRs
    h2_t w2[4][16];
#pragma unroll
    for (int g = 0; g < 4; ++g) {
        const float2* wp = (const float2*)(Wh + (size_t)(g * 128 + u) * HH + ks * 32);
#pragma unroll
        for (int j = 0; j < 16; ++j)
            w2[g][j] = __builtin_amdgcn_cvt_pkrtz(wp[j].x, wp[j].y);
    }

    const float mk0 = (ks == 0) ? 1.f : 0.f;
    const float mk1 = (ks == 1) ? 1.f : 0.f;
    const float mk2 = (ks == 2) ? 1.f : 0.f;
    const float mk3 = (ks == 3) ? 1.f : 0.f;
    const bool istanh = (ks == 2);
    const float GS  = istanh ? 2.f : -1.f;
    const float GC0 = istanh ? 1.f : 0.f;
    const float GC1 = istanh ? -2.f : 1.f;
    const bool ks1 = (ks & 1) != 0;
    const bool ks2 = (ks & 2) != 0;

    if (tid < 80) ((unsigned int*)&hsd[0][0])[tid] = 0u;   // zero buffer 0
    float c = 0.f;
    const int t0 = dir ? (TT - 1) : 0;
    const int tstep = dir ? -1 : 1;
    const int xstride = tstep * BB * G4;
    const int hstride = tstep * BB * HH;
    const float* xqp = xp + ((long long)t0 * BB + b_) * G4 + ks * 128 + u;
    __fp16*      hop = hout + ((long long)t0 * BB + b_) * HH + u;
    float xq = *xqp;
    __syncthreads();

    for (int s = 0; s < TT; ++s) {
        const int rb = s & 1;
        float p0 = mk0 * xq, p1 = mk1 * xq, p2 = mk2 * xq, p3 = mk3 * xq;
        // prefetch next xp now (one-past-end lands in adjacent ws buffer)
        xqp += xstride;
        xq = *xqp;
#pragma unroll
        for (int q = 0; q < 4; ++q) {
            const uint4 hv = *(const uint4*)&hsd[rb][ks * 40 + q * 8];
            const h2_t ha  = bch2(hv.x);
            const h2_t hbv = bch2(hv.y);
            const h2_t hc  = bch2(hv.z);
            const h2_t hd  = bch2(hv.w);
            p0 = __builtin_amdgcn_fdot2(ha,  w2[0][q*4+0], p0, false);
            p0 = __builtin_amdgcn_fdot2(hbv, w2[0][q*4+1], p0, false);
            p0 = __builtin_amdgcn_fdot2(hc,  w2[0][q*4+2], p0, false);
            p0 = __builtin_amdgcn_fdot2(hd,  w2[0][q*4+3], p0, false);
            p1 = __builtin_amdgcn_fdot2(ha,  w2[1][q*4+0], p1, false);
            p1 = __builtin_amdgcn_fdot2(hbv, w2[1][q*4+1], p1, false);
            p1 = __builtin_amdgcn_fdot2(hc,  w2[1][q*4+2], p1, false);
            p1 = __builtin_amdgcn_fdot2(hd,  w2[1][q*4+3], p1, false);
            p2 = __builtin_amdgcn_fdot2(ha,  w2[2][q*4+0], p2, false);
            p2 = __builtin_amdgcn_fdot2(hbv, w2[2][q*4+1], p2, false);
            p2 = __builtin_amdgcn_fdot2(hc,  w2[2][q*4+2], p2, false);
            p2 = __builtin_amdgcn_fdot2(hd,  w2[2][q*4+3], p2, false);
            p3 = __builtin_amdgcn_fdot2(ha,  w2[3][q*4+0], p3, false);
            p3 = __builtin_amdgcn_fdot2(hbv, w2[3][q*4+1], p3, false);
            p3 = __builtin_amdgcn_fdot2(hc,  w2[3][q*4+2], p3, false);
            p3 = __builtin_amdgcn_fdot2(hd,  w2[3][q*4+3], p3, false);
        }
        // quad butterfly: every lane ends with ALL four complete gate sums
        p0 += qxor1(p0); p0 += qxor2(p0);
        p1 += qxor1(p1); p1 += qxor2(p1);
        p2 += qxor1(p2); p2 += qxor2(p2);
        p3 += qxor1(p3); p3 += qxor2(p3);
        // lane ks computes only its gate's nonlinearity, quad_perm regather
        const float pa   = ks1 ? p1 : p0;
        const float pb   = ks1 ? p3 : p2;
        const float psel = ks2 ? pb : pa;
        const float val  = GC0 + GC1 * __builtin_amdgcn_rcpf(1.f + __expf(GS * psel));
        const float gi = qbcast(val, 0);
        const float gf = qbcast(val, 1);
        const float gg = qbcast(val, 2);
        const float go = qbcast(val, 3);
        c = gf * c + gi * gg;
        const float tc = 1.f - 2.f * __builtin_amdgcn_rcpf(1.f + __expf(2.f * c));
        const float hv = go * tc;
        const __fp16 hv16 = (__fp16)hv;
        if (ks == 0) {
            hsd[rb ^ 1][(u >> 5) * 40 + (u & 31)] = hv16;
            *hop = hv16;
        }
        hop += hstride;
        // raw barrier, NO memory clobber: order only LDS (lgkm), leave
        // global store + prefetch load in flight.
        __builtin_amdgcn_sched_barrier(0);
        asm volatile("s_waitcnt lgkmcnt(0)");
        __builtin_amdgcn_s_barrier();
        __builtin_amdgcn_sched_barrier(0);
    }
}

// ---------------------------------------------------------------------------
// K3: emit[t][b][l] = (concat(hf,hb)[t][b][:] . W_out[l,:] + b_out[l]) * mask
// v3: 64 blocks x 8 timesteps each — Wout staged/converted ONCE per block,
// h re-staged per t. f16 fdot2 compute; pitches 132/130 (conflict-free).
// ---------------------------------------------------------------------------
__global__ __launch_bounds__(1024) void k_emit(
    const __fp16* __restrict__ hf, const __fp16* __restrict__ hb,
    const float* __restrict__ Wout, const float* __restrict__ bout,
    const int* __restrict__ charr, float* __restrict__ emit)
{
    __shared__ __align__(16) unsigned int hsm2[BB * 132];   // [b][132] h2-pitch
    __shared__ __align__(16) unsigned int wsm2[LL * 130];   // [l][130] h2-pitch
    const int tchunk = blockIdx.x;          // 0..63 (8 t's each)
    const int tid = threadIdx.x;
    const unsigned int* hfu = (const unsigned int*)hf;
    const unsigned int* hbu = (const unsigned int*)hb;

    // stage Wout once: 32 l x 128 h2 (cvt f32->f16)
    for (int idx = tid; idx < LL * 128; idx += 1024) {
        const int l = idx >> 7, kp = idx & 127;
        const float2 wv = ((const float2*)Wout)[l * 128 + kp];
        wsm2[l * 130 + kp] = __builtin_bit_cast(unsigned int,
            __builtin_amdgcn_cvt_pkrtz(wv.x, wv.y));
    }

    const int b_ = tid >> 5, l = tid & 31;
    const float bias = bout[l];

    for (int i = 0; i < 8; ++i) {
        const int t = tchunk * 8 + i;
        __syncthreads();                    // wsm ready (i=0) / prev compute done
        // stage h: 32 b x 128 h2 (64 from hf, 64 from hb)
        for (int idx = tid; idx < BB * 128; idx += 1024) {
            const int bb_ = idx >> 7, k = idx & 127;
            const unsigned int v = (k < 64)
                ? hfu[((size_t)t * BB + bb_) * 64 + k]
                : hbu[((size_t)t * BB + bb_) * 64 + (k - 64)];
            hsm2[bb_ * 132 + k] = v;
        }
        __syncthreads();
        float acc = bias;
#pragma unroll 8
        for (int q = 0; q < 32; ++q) {
            const uint4 h4 = *(const uint4*)&hsm2[b_ * 132 + q * 4];
            const uint2 wa = *(const uint2*)&wsm2[l * 130 + q * 4];
            const uint2 wb = *(const uint2*)&wsm2[l * 130 + q * 4 + 2];
            acc = __builtin_amdgcn_fdot2(bch2(h4.x), bch2(wa.x), acc, false);
            acc = __builtin_amdgcn_fdot2(bch2(h4.y), bch2(wa.y), acc, false);
            acc = __builtin_amdgcn_fdot2(bch2(h4.z), bch2(wb.x), acc, false);
            acc = __builtin_amdgcn_fdot2(bch2(h4.w), bch2(wb.y), acc, false);
        }
        const float m = (charr[b_ * TT + t] > 0) ? 1.f : 0.f;
        emit[((size_t)t * BB + b_) * LL + l] = acc * m;
    }
}

// ---------------------------------------------------------------------------
// K4: CRF forward + gold score, fused. 32 blocks x 64 threads.
// ---------------------------------------------------------------------------
__global__ __launch_bounds__(64) void k_crf(
    const float* __restrict__ emit, const int* __restrict__ charr,
    const int* __restrict__ y, const float* __restrict__ trans,
    const float* __restrict__ startv, const float* __restrict__ endv,
    float* __restrict__ out)
{
    const int tid = threadIdx.x;             // lanes 32..63 mirror lanes 0..31
    const int b_ = blockIdx.x;
    const int j = tid & 31;

    // ---- gold path score: lane-parallel over t (stride 64) ----
    float sc = 0.f;
    int ms = 0;
    for (int t = tid; t < TT; t += 64) {
        const int yv = y[b_ * TT + t];
        const int m = (charr[b_ * TT + t] > 0);
        if (m) { sc += emit[((size_t)t * BB + b_) * LL + yv]; ms++; }
        if (t + 1 < TT) {
            const int mn = (charr[b_ * TT + t + 1] > 0);
            if (mn) sc += trans[yv * LL + y[b_ * TT + t + 1]];
        }
    }
#pragma unroll
    for (int o = 32; o; o >>= 1) {
        sc += __shfl_xor(sc, o);
        ms += __shfl_xor(ms, o);
    }

    // ---- CRF forward ----
    float et[32];
#pragma unroll
    for (int i = 0; i < 32; ++i) et[i] = __expf(trans[i * LL + j]);

    const float a0 = startv[j] + emit[(size_t)b_ * LL + j];
    float M = a0;
    M = fmaxf(M, __shfl_xor(M, 16));
    M = fmaxf(M, __shfl_xor(M, 8));
    M = fmaxf(M, __shfl_xor(M, 4));
    M = fmaxf(M, __shfl_xor(M, 2));
    M = fmaxf(M, __shfl_xor(M, 1));
    float A = __expf(a0 - M);
    float logsc = M;

    float e_nx = emit[((size_t)1 * BB + b_) * LL + j];
    int   m_nx = charr[b_ * TT + 1];

    for (int t = 1; t < TT; ++t) {
        const float ee = __expf(e_nx);       // off critical chain (prefetched)
        const int m_cur = m_nx;
        if (t + 1 < TT) {
            e_nx = emit[((size_t)(t + 1) * BB + b_) * LL + j];
            m_nx = charr[b_ * TT + t + 1];
        }
        float s0 = 0.f, s1 = 0.f, s2 = 0.f, s3 = 0.f;
#pragma unroll
        for (int i = 0; i < 32; i += 4) {
            s0 = fmaf(__int_as_float(__builtin_amdgcn_readlane(__float_as_int(A), i    )), et[i    ], s0);
            s1 = fmaf(__int_as_float(__builtin_amdgcn_readlane(__float_as_int(A), i + 1)), et[i + 1], s1);
            s2 = fmaf(__int_as_float(__builtin_amdgcn_readlane(__float_as_int(A), i + 2)), et[i + 2], s2);
            s3 = fmaf(__int_as_float(__builtin_amdgcn_readlane(__float_as_int(A), i + 3)), et[i + 3], s3);
        }
        const float Anew = ((s0 + s1) + (s2 + s3)) * ee;
        A = (m_cur > 0) ? Anew : A;
        if ((t & 7) == 0) {                  // renorm every 8 steps
            float S = A;
            S = fmaxf(S, __shfl_xor(S, 16));
            S = fmaxf(S, __shfl_xor(S, 8));
            S = fmaxf(S, __shfl_xor(S, 4));
            S = fmaxf(S, __shfl_xor(S, 2));
            S = fmaxf(S, __shfl_xor(S, 1));
            A *= __builtin_amdgcn_rcpf(S);
            logsc += __logf(S);
        }
    }
    // finalize: alpha_j = log(A_j) + logsc; logZ = LSE_j(alpha_j + end_j)
    const float z = __logf(A) + logsc + endv[j];
    float Mz = z;
    Mz = fmaxf(Mz, __shfl_xor(Mz, 16));
    Mz = fmaxf(Mz, __shfl_xor(Mz, 8));
    Mz = fmaxf(Mz, __shfl_xor(Mz, 4));
    Mz = fmaxf(Mz, __shfl_xor(Mz, 2));
    Mz = fmaxf(Mz, __shfl_xor(Mz, 1));
    float sz = __expf(z - Mz);
    sz += __shfl_xor(sz, 16);
    sz += __shfl_xor(sz, 8);
    sz += __shfl_xor(sz, 4);
    sz += __shfl_xor(sz, 2);
    sz += __shfl_xor(sz, 1);
    if (tid == 0) {
        const float logZ = Mz + __logf(sz);
        int last = ms - 1;
        if (last < 0) last = 0;
        const float gold = startv[y[b_ * TT]] + sc + endv[y[b_ * TT + last]];
        atomicAdd(out, logZ - gold);
    }
}

extern "C" void kernel_launch(void* const* d_in, const int* in_sizes, int n_in,
                              void* d_out, int out_size, void* d_ws, size_t ws_size,
                              hipStream_t stream) {
    (void)in_sizes; (void)n_in; (void)out_size; (void)ws_size;
    const int*   word  = (const int*)d_in[0];
    const int*   charr = (const int*)d_in[1];
    const int*   yv    = (const int*)d_in[2];
    const float* wemb  = (const float*)d_in[3];
    const float* cemb  = (const float*)d_in[4];
    const float* Wihf  = (const float*)d_in[5];
    const float* Whhf  = (const float*)d_in[6];
    const float* bf    = (const float*)d_in[7];
    const float* Wihb  = (const float*)d_in[8];
    const float* Whhb  = (const float*)d_in[9];
    const float* bb    = (const float*)d_in[10];
    const float* Wout  = (const float*)d_in[11];
    const float* bout  = (const float*)d_in[12];
    const float* trans = (const float*)d_in[13];
    const float* startv= (const float*)d_in[14];
    const float* endv  = (const float*)d_in[15];

    float* ws    = (float*)d_ws;
    float* xpf   = ws;                          // [T][B][512] f32
    float* xpb   = xpf + (size_t)TT * BB * G4;
    __fp16* hf16 = (__fp16*)(xpb + (size_t)TT * BB * G4);  // [T][B][128] f16
    __fp16* hb16 = hf16 + (size_t)TT * BB * HH;
    float* emit  = (float*)(hb16 + (size_t)TT * BB * HH);  // [T][B][32] f32

    k_inproj<<<dim3(128, 4), 512, 0, stream>>>(word, charr, wemb, cemb,
                                               Wihf, bf, Wihb, bb, xpf, xpb,
                                               (float*)d_out);
    k_lstm<<<64, 512, 0, stream>>>(xpf, xpb, Whhf, Whhb, hf16, hb16);
    k_emit<<<64, 1024, 0, stream>>>(hf16, hb16, Wout, bout, charr, emit);
    k_crf<<<32, 64, 0, stream>>>(emit, charr, yv, trans, startv, endv,
                                 (float*)d_out);
}

// Round 14
// 435.637 us; speedup vs baseline: 1.4352x; 1.0633x over previous
//
#include <hip/hip_runtime.h>
#include <math.h>

#define BB 32
#define TT 512
#define DW 128
#define DC 64
#define DD 192
#define HH 128
#define G4 512
#define LL 32

typedef __fp16 h2_t __attribute__((ext_vector_type(2)));

__device__ __forceinline__ h2_t bch2(unsigned int x) { return __builtin_bit_cast(h2_t, x); }

// quad_perm lane-xor via DPP (VALU, not LDS)
__device__ __forceinline__ float qxor1(float x) {
    return __int_as_float(__builtin_amdgcn_update_dpp(0, __float_as_int(x), 0xB1, 0xF, 0xF, true));
}
__device__ __forceinline__ float qxor2(float x) {
    return __int_as_float(__builtin_amdgcn_update_dpp(0, __float_as_int(x), 0x4E, 0xF, 0xF, true));
}
// quad_perm broadcast of lane q (within each quad)
__device__ __forceinline__ float qbcast(float x, int ctrl_imm) {
    switch (ctrl_imm) {
        case 0: return __int_as_float(__builtin_amdgcn_update_dpp(0, __float_as_int(x), 0x00, 0xF, 0xF, true));
        case 1: return __int_as_float(__builtin_amdgcn_update_dpp(0, __float_as_int(x), 0x55, 0xF, 0xF, true));
        case 2: return __int_as_float(__builtin_amdgcn_update_dpp(0, __float_as_int(x), 0xAA, 0xF, 0xF, true));
        default:return __int_as_float(__builtin_amdgcn_update_dpp(0, __float_as_int(x), 0xFF, 0xF, 0xF, true));
    }
}

// ---------------------------------------------------------------------------
// K1: fused embedding-gather + input projection GEMM, f16 dot2, single-stage.
// Also zeroes out[0] (needed by k_crf's atomicAdd).
// ---------------------------------------------------------------------------
__global__ __launch_bounds__(512) void k_inproj(
    const int* __restrict__ word, const int* __restrict__ charr,
    const float* __restrict__ wemb, const float* __restrict__ cemb,
    const float* __restrict__ Wf, const float* __restrict__ bf,
    const float* __restrict__ Wb, const float* __restrict__ bb,
    float* __restrict__ xpf, float* __restrict__ xpb,
    float* __restrict__ out)
{
    __shared__ __align__(16) h2_t As2[96][132];   // [k-pair][token-row]
    __shared__ __align__(16) h2_t Bs2[96][260];   // [k-pair][gate-col]
    const int tid = threadIdx.x;
    const int ntile = blockIdx.x;           // 0..127
    const int ctile = blockIdx.y;           // 0..3
    if (ntile == 0 && ctile == 0 && tid == 0) out[0] = 0.f;
    const int dir = ctile >> 1;
    const float* W = dir ? Wb : Wf;
    const float* bias = dir ? bb : bf;
    float* xp = dir ? xpb : xpf;
    const int colbase = (ctile & 1) * 256;  // within the 512 gate-cols

    // ---- stage A: 128 tokens x 192 floats -> h2 (4 threads per row) ----
    {
        const int lrow = tid >> 2;          // 0..127
        const int lq   = tid & 3;
        const int nA   = ntile * 128 + lrow;
        const int wi   = word[nA];
        const int ci   = charr[nA];
#pragma unroll
        for (int kc = 0; kc < 12; ++kc) {
            const int k0 = kc * 16 + lq * 4;
            float4 av;
            if (k0 < DW) av = *(const float4*)(wemb + (size_t)wi * DW + k0);
            else         av = *(const float4*)(cemb + (size_t)ci * DC + (k0 - DW));
            const int kp = k0 >> 1;
            As2[kp    ][lrow] = __builtin_amdgcn_cvt_pkrtz(av.x, av.y);
            As2[kp + 1][lrow] = __builtin_amdgcn_cvt_pkrtz(av.z, av.w);
        }
    }
    // ---- stage B: 256 gate-cols x 192 floats -> h2 (2 threads per col) ----
    {
        const int lcol = tid >> 1;          // 0..255
        const int lh   = tid & 1;
        const int g    = colbase + lcol;
#pragma unroll
        for (int kc = 0; kc < 24; ++kc) {
            const int k0 = kc * 8 + lh * 4;
            const float4 bv = *(const float4*)(W + (size_t)g * DD + k0);
            const int kp = k0 >> 1;
            Bs2[kp    ][lcol] = __builtin_amdgcn_cvt_pkrtz(bv.x, bv.y);
            Bs2[kp + 1][lcol] = __builtin_amdgcn_cvt_pkrtz(bv.z, bv.w);
        }
    }
    __syncthreads();

    // ---- compute: 8x8 outputs per thread over 96 k-pairs, no barriers ----
    const int tr = tid >> 5;    // 0..15  (token block)
    const int tc = tid & 31;    // 0..31  (col block)
    float acc[8][8];
#pragma unroll
    for (int i = 0; i < 8; ++i)
#pragma unroll
        for (int j = 0; j < 8; ++j) acc[i][j] = 0.f;

    for (int kc = 0; kc < 24; ++kc) {
#pragma unroll
        for (int kq = 0; kq < 4; ++kq) {
            const int kp = kc * 4 + kq;
            h2_t __attribute__((aligned(16))) a2[8], b2[8];
            *(uint4*)&a2[0] = *(const uint4*)&As2[kp][tr * 8];
            *(uint4*)&a2[4] = *(const uint4*)&As2[kp][tr * 8 + 4];
            *(uint4*)&b2[0] = *(const uint4*)&Bs2[kp][tc * 8];
            *(uint4*)&b2[4] = *(const uint4*)&Bs2[kp][tc * 8 + 4];
#pragma unroll
            for (int i = 0; i < 8; ++i)
#pragma unroll
                for (int j = 0; j < 8; ++j)
                    acc[i][j] = __builtin_amdgcn_fdot2(a2[i], b2[j], acc[i][j], false);
        }
    }
#pragma unroll
    for (int i = 0; i < 8; ++i) {
        const int n  = ntile * 128 + tr * 8 + i;
        const int b_ = n >> 9, t_ = n & 511;
        float* dst = xp + ((size_t)(t_ * BB + b_)) * G4 + colbase + tc * 8;
#pragma unroll
        for (int j = 0; j < 8; ++j) dst[j] = acc[i][j] + bias[colbase + tc * 8 + j];
    }
}

// ---------------------------------------------------------------------------
// K2: LSTM scan (R7/R11 structure — best measured: 268 us). 64 blocks,
// 512 threads, thread (u=tid>>2, ks=tid&3), weights resident (64 VGPRs),
// 88-VGPR envelope at 2 waves/SIMD. hout stored as __fp16.
// ---------------------------------------------------------------------------
__global__ __launch_bounds__(512)
__attribute__((amdgpu_waves_per_eu(2, 2)))
void k_lstm(
    const float* __restrict__ xpf, const float* __restrict__ xpb,
    const float* __restrict__ Whf, const float* __restrict__ Whb,
    __fp16* __restrict__ hf, __fp16* __restrict__ hb)
{
    // [buf][ks*40 + j] f16 units; per-ks block = 80 B -> conflict-free.
    __shared__ __align__(16) __fp16 hsd[2][160];
    const int tid = threadIdx.x;
    const int dir = blockIdx.x >> 5;
    const int b_  = blockIdx.x & 31;
    const float* xp = dir ? xpb : xpf;
    const float* Wh = dir ? Whb : Whf;
    __fp16* hout = dir ? hb : hf;
    const int ks = tid & 3;          // k-quarter (32 wide) == owned gate id
    const int u  = tid >> 2;         // hidden unit 0..127

    // W_hh[g*128+u][ks*32 .. +31] for g=0..3 as packed half2: 4x16 = 64 VGPRs
    h2_t w2[4][16];
#pragma unroll
    for (int g = 0; g < 4; ++g) {
        const float2* wp = (const float2*)(Wh + (size_t)(g * 128 + u) * HH + ks * 32);
#pragma unroll
        for (int j = 0; j < 16; ++j)
            w2[g][j] = __builtin_amdgcn_cvt_pkrtz(wp[j].x, wp[j].y);
    }

    const float mk0 = (ks == 0) ? 1.f : 0.f;
    const float mk1 = (ks == 1) ? 1.f : 0.f;
    const float mk2 = (ks == 2) ? 1.f : 0.f;
    const float mk3 = (ks == 3) ? 1.f : 0.f;
    const bool istanh = (ks == 2);
    const float GS  = istanh ? 2.f : -1.f;
    const float GC0 = istanh ? 1.f : 0.f;
    const float GC1 = istanh ? -2.f : 1.f;
    const bool ks1 = (ks & 1) != 0;
    const bool ks2 = (ks & 2) != 0;

    if (tid < 80) ((unsigned int*)&hsd[0][0])[tid] = 0u;   // zero buffer 0
    float c = 0.f;
    const int t0 = dir ? (TT - 1) : 0;
    const int tstep = dir ? -1 : 1;
    const int xstride = tstep * BB * G4;
    const int hstride = tstep * BB * HH;
    const float* xqp = xp + ((long long)t0 * BB + b_) * G4 + ks * 128 + u;
    __fp16*      hop = hout + ((long long)t0 * BB + b_) * HH + u;
    float xq = *xqp;
    __syncthreads();

    for (int s = 0; s < TT; ++s) {
        const int rb = s & 1;
        float p0 = mk0 * xq, p1 = mk1 * xq, p2 = mk2 * xq, p3 = mk3 * xq;
        // prefetch next xp now (one-past-end lands in adjacent ws buffer)
        xqp += xstride;
        xq = *xqp;
#pragma unroll
        for (int q = 0; q < 4; ++q) {
            const uint4 hv = *(const uint4*)&hsd[rb][ks * 40 + q * 8];
            const h2_t ha  = bch2(hv.x);
            const h2_t hbv = bch2(hv.y);
            const h2_t hc  = bch2(hv.z);
            const h2_t hd  = bch2(hv.w);
            p0 = __builtin_amdgcn_fdot2(ha,  w2[0][q*4+0], p0, false);
            p0 = __builtin_amdgcn_fdot2(hbv, w2[0][q*4+1], p0, false);
            p0 = __builtin_amdgcn_fdot2(hc,  w2[0][q*4+2], p0, false);
            p0 = __builtin_amdgcn_fdot2(hd,  w2[0][q*4+3], p0, false);
            p1 = __builtin_amdgcn_fdot2(ha,  w2[1][q*4+0], p1, false);
            p1 = __builtin_amdgcn_fdot2(hbv, w2[1][q*4+1], p1, false);
            p1 = __builtin_amdgcn_fdot2(hc,  w2[1][q*4+2], p1, false);
            p1 = __builtin_amdgcn_fdot2(hd,  w2[1][q*4+3], p1, false);
            p2 = __builtin_amdgcn_fdot2(ha,  w2[2][q*4+0], p2, false);
            p2 = __builtin_amdgcn_fdot2(hbv, w2[2][q*4+1], p2, false);
            p2 = __builtin_amdgcn_fdot2(hc,  w2[2][q*4+2], p2, false);
            p2 = __builtin_amdgcn_fdot2(hd,  w2[2][q*4+3], p2, false);
            p3 = __builtin_amdgcn_fdot2(ha,  w2[3][q*4+0], p3, false);
            p3 = __builtin_amdgcn_fdot2(hbv, w2[3][q*4+1], p3, false);
            p3 = __builtin_amdgcn_fdot2(hc,  w2[3][q*4+2], p3, false);
            p3 = __builtin_amdgcn_fdot2(hd,  w2[3][q*4+3], p3, false);
        }
        // quad butterfly: every lane ends with ALL four complete gate sums
        p0 += qxor1(p0); p0 += qxor2(p0);
        p1 += qxor1(p1); p1 += qxor2(p1);
        p2 += qxor1(p2); p2 += qxor2(p2);
        p3 += qxor1(p3); p3 += qxor2(p3);
        // lane ks computes only its gate's nonlinearity, quad_perm regather
        const float pa   = ks1 ? p1 : p0;
        const float pb   = ks1 ? p3 : p2;
        const float psel = ks2 ? pb : pa;
        const float val  = GC0 + GC1 * __builtin_amdgcn_rcpf(1.f + __expf(GS * psel));
        const float gi = qbcast(val, 0);
        const float gf = qbcast(val, 1);
        const float gg = qbcast(val, 2);
        const float go = qbcast(val, 3);
        c = gf * c + gi * gg;
        const float tc = 1.f - 2.f * __builtin_amdgcn_rcpf(1.f + __expf(2.f * c));
        const float hv = go * tc;
        const __fp16 hv16 = (__fp16)hv;
        if (ks == 0) {
            hsd[rb ^ 1][(u >> 5) * 40 + (u & 31)] = hv16;
            *hop = hv16;
        }
        hop += hstride;
        // raw barrier, NO memory clobber: order only LDS (lgkm), leave
        // global store + prefetch load in flight.
        __builtin_amdgcn_sched_barrier(0);
        asm volatile("s_waitcnt lgkmcnt(0)");
        __builtin_amdgcn_s_barrier();
        __builtin_amdgcn_sched_barrier(0);
    }
}

// ---------------------------------------------------------------------------
// K3: emit[t][b][l] = (concat(hf,hb)[t][b][:] . W_out[l,:] + b_out[l]) * mask
// R11 version (measured best): 512 blocks (one per t), f16 staging + fdot2;
// hsm pitch 132 / wsm pitch 130 dwords -> 2-way bank alias (free).
// ---------------------------------------------------------------------------
__global__ __launch_bounds__(1024) void k_emit(
    const __fp16* __restrict__ hf, const __fp16* __restrict__ hb,
    const float* __restrict__ Wout, const float* __restrict__ bout,
    const int* __restrict__ charr, float* __restrict__ emit)
{
    __shared__ __align__(16) unsigned int hsm2[BB * 132];   // [b][132] h2-pitch
    __shared__ __align__(16) unsigned int wsm2[LL * 130];   // [l][130] h2-pitch
    const int t = blockIdx.x;
    const int tid = threadIdx.x;
    // stage h: 32 b x 128 h2 (64 from hf, 64 from hb)
    const unsigned int* hfu = (const unsigned int*)hf;
    const unsigned int* hbu = (const unsigned int*)hb;
    for (int idx = tid; idx < BB * 128; idx += 1024) {
        const int b_ = idx >> 7, k = idx & 127;
        const unsigned int v = (k < 64)
            ? hfu[((size_t)t * BB + b_) * 64 + k]
            : hbu[((size_t)t * BB + b_) * 64 + (k - 64)];
        hsm2[b_ * 132 + k] = v;
    }
    // stage Wout: 32 l x 128 h2 (cvt f32->f16)
    for (int idx = tid; idx < LL * 128; idx += 1024) {
        const int l = idx >> 7, kp = idx & 127;
        const float2 wv = ((const float2*)Wout)[l * 128 + kp];
        wsm2[l * 130 + kp] = __builtin_bit_cast(unsigned int,
            __builtin_amdgcn_cvt_pkrtz(wv.x, wv.y));
    }
    __syncthreads();
    const int b_ = tid >> 5, l = tid & 31;
    float acc = bout[l];
#pragma unroll 8
    for (int q = 0; q < 32; ++q) {
        const uint4 h4 = *(const uint4*)&hsm2[b_ * 132 + q * 4];
        const uint2 wa = *(const uint2*)&wsm2[l * 130 + q * 4];
        const uint2 wb = *(const uint2*)&wsm2[l * 130 + q * 4 + 2];
        acc = __builtin_amdgcn_fdot2(bch2(h4.x), bch2(wa.x), acc, false);
        acc = __builtin_amdgcn_fdot2(bch2(h4.y), bch2(wa.y), acc, false);
        acc = __builtin_amdgcn_fdot2(bch2(h4.z), bch2(wb.x), acc, false);
        acc = __builtin_amdgcn_fdot2(bch2(h4.w), bch2(wb.y), acc, false);
    }
    const float m = (charr[b_ * TT + t] > 0) ? 1.f : 0.f;
    emit[((size_t)t * BB + b_) * LL + l] = acc * m;
}

// ---------------------------------------------------------------------------
// K4: CRF forward + gold score, fused. 32 blocks x 64 threads.
// ---------------------------------------------------------------------------
__global__ __launch_bounds__(64) void k_crf(
    const float* __restrict__ emit, const int* __restrict__ charr,
    const int* __restrict__ y, const float* __restrict__ trans,
    const float* __restrict__ startv, const float* __restrict__ endv,
    float* __restrict__ out)
{
    const int tid = threadIdx.x;             // lanes 32..63 mirror lanes 0..31
    const int b_ = blockIdx.x;
    const int j = tid & 31;

    // ---- gold path score: lane-parallel over t (stride 64) ----
    float sc = 0.f;
    int ms = 0;
    for (int t = tid; t < TT; t += 64) {
        const int yv = y[b_ * TT + t];
        const int m = (charr[b_ * TT + t] > 0);
        if (m) { sc += emit[((size_t)t * BB + b_) * LL + yv]; ms++; }
        if (t + 1 < TT) {
            const int mn = (charr[b_ * TT + t + 1] > 0);
            if (mn) sc += trans[yv * LL + y[b_ * TT + t + 1]];
        }
    }
#pragma unroll
    for (int o = 32; o; o >>= 1) {
        sc += __shfl_xor(sc, o);
        ms += __shfl_xor(ms, o);
    }

    // ---- CRF forward ----
    float et[32];
#pragma unroll
    for (int i = 0; i < 32; ++i) et[i] = __expf(trans[i * LL + j]);

    const float a0 = startv[j] + emit[(size_t)b_ * LL + j];
    float M = a0;
    M = fmaxf(M, __shfl_xor(M, 16));
    M = fmaxf(M, __shfl_xor(M, 8));
    M = fmaxf(M, __shfl_xor(M, 4));
    M = fmaxf(M, __shfl_xor(M, 2));
    M = fmaxf(M, __shfl_xor(M, 1));
    float A = __expf(a0 - M);
    float logsc = M;

    float e_nx = emit[((size_t)1 * BB + b_) * LL + j];
    int   m_nx = charr[b_ * TT + 1];

    for (int t = 1; t < TT; ++t) {
        const float ee = __expf(e_nx);       // off critical chain (prefetched)
        const int m_cur = m_nx;
        if (t + 1 < TT) {
            e_nx = emit[((size_t)(t + 1) * BB + b_) * LL + j];
            m_nx = charr[b_ * TT + t + 1];
        }
        float s0 = 0.f, s1 = 0.f, s2 = 0.f, s3 = 0.f;
#pragma unroll
        for (int i = 0; i < 32; i += 4) {
            s0 = fmaf(__int_as_float(__builtin_amdgcn_readlane(__float_as_int(A), i    )), et[i    ], s0);
            s1 = fmaf(__int_as_float(__builtin_amdgcn_readlane(__float_as_int(A), i + 1)), et[i + 1], s1);
            s2 = fmaf(__int_as_float(__builtin_amdgcn_readlane(__float_as_int(A), i + 2)), et[i + 2], s2);
            s3 = fmaf(__int_as_float(__builtin_amdgcn_readlane(__float_as_int(A), i + 3)), et[i + 3], s3);
        }
        const float Anew = ((s0 + s1) + (s2 + s3)) * ee;
        A = (m_cur > 0) ? Anew : A;
        if ((t & 7) == 0) {                  // renorm every 8 steps
            float S = A;
            S = fmaxf(S, __shfl_xor(S, 16));
            S = fmaxf(S, __shfl_xor(S, 8));
            S = fmaxf(S, __shfl_xor(S, 4));
            S = fmaxf(S, __shfl_xor(S, 2));
            S = fmaxf(S, __shfl_xor(S, 1));
            A *= __builtin_amdgcn_rcpf(S);
            logsc += __logf(S);
        }
    }
    // finalize: alpha_j = log(A_j) + logsc; logZ = LSE_j(alpha_j + end_j)
    const float z = __logf(A) + logsc + endv[j];
    float Mz = z;
    Mz = fmaxf(Mz, __shfl_xor(Mz, 16));
    Mz = fmaxf(Mz, __shfl_xor(Mz, 8));
    Mz = fmaxf(Mz, __shfl_xor(Mz, 4));
    Mz = fmaxf(Mz, __shfl_xor(Mz, 2));
    Mz = fmaxf(Mz, __shfl_xor(Mz, 1));
    float sz = __expf(z - Mz);
    sz += __shfl_xor(sz, 16);
    sz += __shfl_xor(sz, 8);
    sz += __shfl_xor(sz, 4);
    sz += __shfl_xor(sz, 2);
    sz += __shfl_xor(sz, 1);
    if (tid == 0) {
        const float logZ = Mz + __logf(sz);
        int last = ms - 1;
        if (last < 0) last = 0;
        const float gold = startv[y[b_ * TT]] + sc + endv[y[b_ * TT + last]];
        atomicAdd(out, logZ - gold);
    }
}

extern "C" void kernel_launch(void* const* d_in, const int* in_sizes, int n_in,
                              void* d_out, int out_size, void* d_ws, size_t ws_size,
                              hipStream_t stream) {
    (void)in_sizes; (void)n_in; (void)out_size; (void)ws_size;
    const int*   word  = (const int*)d_in[0];
    const int*   charr = (const int*)d_in[1];
    const int*   yv    = (const int*)d_in[2];
    const float* wemb  = (const float*)d_in[3];
    const float* cemb  = (const float*)d_in[4];
    const float* Wihf  = (const float*)d_in[5];
    const float* Whhf  = (const float*)d_in[6];
    const float* bf    = (const float*)d_in[7];
    const float* Wihb  = (const float*)d_in[8];
    const float* Whhb  = (const float*)d_in[9];
    const float* bb    = (const float*)d_in[10];
    const float* Wout  = (const float*)d_in[11];
    const float* bout  = (const float*)d_in[12];
    const float* trans = (const float*)d_in[13];
    const float* startv= (const float*)d_in[14];
    const float* endv  = (const float*)d_in[15];

    float* ws    = (float*)d_ws;
    float* xpf   = ws;                          // [T][B][512] f32
    float* xpb   = xpf + (size_t)TT * BB * G4;
    __fp16* hf16 = (__fp16*)(xpb + (size_t)TT * BB * G4);  // [T][B][128] f16
    __fp16* hb16 = hf16 + (size_t)TT * BB * HH;
    float* emit  = (float*)(hb16 + (size_t)TT * BB * HH);  // [T][B][32] f32

    k_inproj<<<dim3(128, 4), 512, 0, stream>>>(word, charr, wemb, cemb,
                                               Wihf, bf, Wihb, bb, xpf, xpb,
                                               (float*)d_out);
    k_lstm<<<64, 512, 0, stream>>>(xpf, xpb, Whhf, Whhb, hf16, hb16);
    k_emit<<<TT, 1024, 0, stream>>>(hf16, hb16, Wout, bout, charr, emit);
    k_crf<<<32, 64, 0, stream>>>(emit, charr, yv, trans, startv, endv,
                                 (float*)d_out);
}